// Round 11
// baseline (648.440 us; speedup 1.0000x reference)
//
#include <hip/hip_runtime.h>
#include <hip/hip_bf16.h>
#include <cstdint>

#define F_IN 256
#define C 128
#define NBUK_MAX 320     // supports NODES <= 81920 (bucket = dst >> 8)
#define CHUNK 4096       // edges per partition block

typedef short bf8_t __attribute__((ext_vector_type(8)));   // 8 bf16 bit-patterns (4 VGPRs)
typedef float f4_t  __attribute__((ext_vector_type(4)));

static inline size_t align256(size_t x) { return (x + 255) & ~(size_t)255; }

// ---------------- graph preprocessing ----------------

// Pass A: per-chunk bucket histogram (LDS), accumulated into global btot (266 ints).
__global__ __launch_bounds__(256) void histA_kernel(const int* __restrict__ dst,
                                                    int* __restrict__ btot,
                                                    int E, int nbuk) {
    __shared__ int hist[NBUK_MAX];
    const int tid = threadIdx.x;
    const int e0 = blockIdx.x * CHUNK;
    for (int i = tid; i < NBUK_MAX; i += 256) hist[i] = 0;
    __syncthreads();
#pragma unroll
    for (int k = 0; k < CHUNK / 256; ++k) {
        int e = e0 + k * 256 + tid;
        if (e < E) atomicAdd(&hist[dst[e] >> 8], 1);
    }
    __syncthreads();
    for (int i = tid; i < nbuk; i += 256) {
        int h = hist[i];
        if (h) atomicAdd(&btot[i], h);
    }
}

// Pass B: single block: exclusive-scan 266 bucket totals (wave-0 shuffle scan).
__global__ __launch_bounds__(256) void bscan_kernel(const int* __restrict__ btot,
                                                    int nbuk,
                                                    int* __restrict__ ebase,
                                                    int* __restrict__ gcur) {
    __shared__ int sums[NBUK_MAX];
    __shared__ int base[NBUK_MAX + 1];
    const int tid = threadIdx.x;
    for (int bk = tid; bk < NBUK_MAX; bk += 256)
        sums[bk] = (bk < nbuk) ? btot[bk] : 0;
    __syncthreads();
    if (tid < 64) {
        int acc[5];
        int s = 0;
#pragma unroll
        for (int j = 0; j < 5; ++j) {
            acc[j] = s;
            s += sums[tid * 5 + j];
        }
        int tot = s;
#pragma unroll
        for (int d = 1; d < 64; d <<= 1) {
            int o = __shfl_up(tot, d);
            if (tid >= d) tot += o;
        }
        int excl = tot - s;
#pragma unroll
        for (int j = 0; j < 5; ++j) base[tid * 5 + j] = excl + acc[j];
        if (tid == 63) base[320] = tot;
    }
    __syncthreads();
    for (int bk = tid; bk <= nbuk; bk += 256) {
        ebase[bk] = base[bk];
        if (bk < nbuk) gcur[bk] = base[bk];
    }
}

// Pass 1: partition edges by bucket (dst>>8) with LDS staging -> grouped writes.
__global__ __launch_bounds__(256) void partition_kernel(const int* __restrict__ src,
                                                        const int* __restrict__ dst,
                                                        int* __restrict__ gcur,
                                                        int2* __restrict__ ebuf, int E) {
    __shared__ int hist[NBUK_MAX];
    __shared__ int base[NBUK_MAX];
    __shared__ int gbase[NBUK_MAX];
    __shared__ int2 stage[CHUNK];
    const int tid = threadIdx.x;
    const int e0 = blockIdx.x * CHUNK;
    const int cnt = min(CHUNK, E - e0);

    for (int i = tid; i < NBUK_MAX; i += 256) hist[i] = 0;
    __syncthreads();

    int2 ev[CHUNK / 256];
    int mo[CHUNK / 256];
#pragma unroll
    for (int k = 0; k < CHUNK / 256; ++k) {
        int e = e0 + k * 256 + tid;
        if (e < E) {
            int2 v;
            v.x = src[e];
            v.y = dst[e];
            ev[k] = v;
            mo[k] = atomicAdd(&hist[v.y >> 8], 1);
        }
    }
    __syncthreads();
    // exclusive scan of hist (320 entries) by wave 0: 5 buckets/lane + shuffle scan
    if (tid < 64) {
        int acc[5];
        int s = 0;
#pragma unroll
        for (int j = 0; j < 5; ++j) {
            int idx = tid * 5 + j;
            acc[j] = s;
            s += hist[idx];
        }
        int tot = s;
#pragma unroll
        for (int d = 1; d < 64; d <<= 1) {
            int o = __shfl_up(tot, d);
            if (tid >= d) tot += o;
        }
        int excl = tot - s;
#pragma unroll
        for (int j = 0; j < 5; ++j) base[tid * 5 + j] = excl + acc[j];
    }
    __syncthreads();
    // reserve global ranges (one atomic per nonempty bucket)
    for (int i = tid; i < NBUK_MAX; i += 256) {
        int h = hist[i];
        gbase[i] = h ? atomicAdd(&gcur[i], h) : 0;
    }
    __syncthreads();
    // scatter into LDS staging grouped by bucket
#pragma unroll
    for (int k = 0; k < CHUNK / 256; ++k) {
        int e = e0 + k * 256 + tid;
        if (e < E) stage[base[ev[k].y >> 8] + mo[k]] = ev[k];
    }
    __syncthreads();
    // grouped write-out: consecutive staged entries -> consecutive global slots
    for (int i = tid; i < cnt; i += 256) {
        int2 e = stage[i];
        int b = e.y >> 8;
        ebuf[gbase[b] + (i - base[b])] = e;
    }
}

// Pass 2: per-bucket CSR build. Counts per-node degree in LDS, local scan -> offs,
// dinv, CSR fill with self-loop head. All node-level work confined to the bucket.
__global__ __launch_bounds__(256) void csr_build_kernel(const int2* __restrict__ ebuf,
                                                        const int* __restrict__ ebase,
                                                        int* __restrict__ offs,
                                                        float* __restrict__ dinv,
                                                        int* __restrict__ csr, int nodes) {
    __shared__ int deg[256];
    __shared__ int p[256];
    __shared__ int pre[257];   // exclusive prefix of deg
    __shared__ int cur[256];
    const int b = blockIdx.x;
    const int n0 = b << 8;
    const int ncnt = min(256, nodes - n0);
    const int tid = threadIdx.x;
    const int eb = ebase[b], ee = ebase[b + 1];

    deg[tid] = 0;
    __syncthreads();
    for (int i = eb + tid; i < ee; i += 256)
        atomicAdd(&deg[ebuf[i].y & 255], 1);
    __syncthreads();
    p[tid] = deg[tid];
    __syncthreads();
    for (int d = 1; d < 256; d <<= 1) {
        int v = (tid >= d) ? p[tid - d] : 0;
        __syncthreads();
        p[tid] += v;
        __syncthreads();
    }
    pre[tid + 1] = p[tid];
    if (tid == 0) pre[0] = 0;
    __syncthreads();

    // offs[n0+i] = eb + pre[i] + n0 + i  (each preceding node adds 1 self-loop)
    for (int i = tid; i <= ncnt; i += 256)
        offs[n0 + i] = eb + pre[i] + n0 + i;
    if (tid < ncnt) {
        dinv[n0 + tid] = rsqrtf((float)(deg[tid] + 1));
        csr[eb + pre[tid] + n0 + tid] = n0 + tid;   // self-loop head
    }
    cur[tid] = 0;
    __syncthreads();
    for (int i = eb + tid; i < ee; i += 256) {
        int2 e = ebuf[i];
        int loc = e.y & 255;
        int q = atomicAdd(&cur[loc], 1);
        csr[eb + pre[loc] + n0 + loc + 1 + q] = e.x;
    }
}

// ---------------- W swizzle: fp32 [K,128] -> bf16 MFMA B-frag order ----------------
// entry id i = (t*8 + u)*64 + l  ->  8 bf16: W[t*32 + (l>>4)*8 + j][u*16 + (l&15)]
static __device__ inline unsigned pack_bf16(float a, float b) {
    __hip_bfloat162 h = __float22bfloat162_rn(make_float2(a, b));
    return *(unsigned*)&h;
}

__global__ void wswz_kernel(const float* __restrict__ W, __hip_bfloat16* __restrict__ Wsw,
                            int K) {
    int i = blockIdx.x * blockDim.x + threadIdx.x;
    int total = (K >> 5) * 8 * 64;
    if (i < total) {
        int l = i & 63;
        int u = (i >> 6) & 7;
        int t = i >> 9;
        int krow = t * 32 + (l >> 4) * 8;
        int col = u * 16 + (l & 15);
        unsigned packed[4];
#pragma unroll
        for (int j = 0; j < 4; ++j) {
            float a = W[(size_t)(krow + 2 * j) * C + col];
            float b = W[(size_t)(krow + 2 * j + 1) * C + col];
            packed[j] = pack_bf16(a, b);
        }
        uint4 o = make_uint4(packed[0], packed[1], packed[2], packed[3]);
        *(uint4*)(Wsw + (size_t)i * 8) = o;
    }
}

// ---------------- MFMA GEMM: G[M,128] = bf16( dinv[row] * (X[M,K] @ W) ) ----------------
// block: 256 threads = 4 waves, 128 rows (2 m-tiles/wave); W in LDS; A prefetch 1 K-step.

static __device__ inline bf8_t pack8(float4 u0, float4 u1) {
    union { unsigned u[4]; bf8_t v; } r;
    r.u[0] = pack_bf16(u0.x, u0.y);
    r.u[1] = pack_bf16(u0.z, u0.w);
    r.u[2] = pack_bf16(u1.x, u1.y);
    r.u[3] = pack_bf16(u1.z, u1.w);
    return r.v;
}

template <bool F32IN>
__global__ __launch_bounds__(256) void mfma_gemm_kernel(const void* __restrict__ Xv,
                                                        const __hip_bfloat16* __restrict__ Wsw,
                                                        const float* __restrict__ dinv,
                                                        __hip_bfloat16* __restrict__ G,
                                                        int M, int K) {
    extern __shared__ char lds[];   // K*256 bytes
    const int tid = threadIdx.x;
    const int l = tid & 63;
    const int w = tid >> 6;
    const int lm = l & 15;
    const int lk = (l >> 4) * 8;
    const int row0 = blockIdx.x * 128 + w * 32;

    const int bytes = K * 256;
    for (int o = tid * 16; o < bytes; o += 256 * 16)
        *(uint4*)(lds + o) = *(const uint4*)((const char*)Wsw + o);
    __syncthreads();

    f4_t acc[2][8] = {};
    const int steps = K >> 5;

    const float* xf[2];
    const __hip_bfloat16* xb[2];
#pragma unroll
    for (int mt = 0; mt < 2; ++mt) {
        int r = min(row0 + mt * 16 + lm, M - 1);
        xf[mt] = (const float*)Xv + (size_t)r * K + lk;
        xb[mt] = (const __hip_bfloat16*)Xv + (size_t)r * K + lk;
    }

    float4 cf[2][2];
    bf8_t cb[2];
#pragma unroll
    for (int mt = 0; mt < 2; ++mt) {
        if (F32IN) {
            cf[mt][0] = *(const float4*)(xf[mt]);
            cf[mt][1] = *(const float4*)(xf[mt] + 4);
        } else {
            cb[mt] = *(const bf8_t*)(xb[mt]);
        }
    }

    for (int t = 0; t < steps; ++t) {
        float4 nf[2][2];
        bf8_t nb[2];
        if (t + 1 < steps) {
#pragma unroll
            for (int mt = 0; mt < 2; ++mt) {
                if (F32IN) {
                    nf[mt][0] = *(const float4*)(xf[mt] + (t + 1) * 32);
                    nf[mt][1] = *(const float4*)(xf[mt] + (t + 1) * 32 + 4);
                } else {
                    nb[mt] = *(const bf8_t*)(xb[mt] + (t + 1) * 32);
                }
            }
        }
        bf8_t a[2];
#pragma unroll
        for (int mt = 0; mt < 2; ++mt)
            a[mt] = F32IN ? pack8(cf[mt][0], cf[mt][1]) : cb[mt];

        const char* bbase = lds + ((size_t)(t * 8) * 64 + l) * 16;
#pragma unroll
        for (int u = 0; u < 8; ++u) {
            bf8_t b = *(const bf8_t*)(bbase + (size_t)u * 64 * 16);
#pragma unroll
            for (int mt = 0; mt < 2; ++mt)
                acc[mt][u] = __builtin_amdgcn_mfma_f32_16x16x32_bf16(a[mt], b, acc[mt][u], 0, 0, 0);
        }
#pragma unroll
        for (int mt = 0; mt < 2; ++mt) {
            if (F32IN) {
                cf[mt][0] = nf[mt][0];
                cf[mt][1] = nf[mt][1];
            } else {
                cb[mt] = nb[mt];
            }
        }
    }

    // epilogue: C/D map col=lane&15, row=(lane>>4)*4+reg; scale by dinv[row]
#pragma unroll
    for (int mt = 0; mt < 2; ++mt) {
        int rbase = row0 + mt * 16 + (l >> 4) * 4;
#pragma unroll
        for (int r = 0; r < 4; ++r) {
            int row = rbase + r;
            if (row < M) {
                float dv = dinv[row];
#pragma unroll
                for (int u = 0; u < 8; ++u) {
                    float v = acc[mt][u][r] * dv;
                    G[(size_t)row * C + u * 16 + lm] = __float2bfloat16(v);
                }
            }
        }
    }
}

// ---------------- aggregation: A[i] = relu(dinv[i]*sum_{j in csr[i]} G[j] + bias) ----------------
// Channel-chunked for L2 temporal locality: blockIdx.y = chunk p (32 channels = one
// 64B line of each G row); per chunk-pass the gather working set is NODES*64B ~ 4.3MB,
// which fits an XCD L2. Wave = 4 node-groups x 16 lanes; per edge each group fetches
// exactly one line. Per-channel summation order identical to before.
__global__ __launch_bounds__(256) void agg_kernel(const __hip_bfloat16* __restrict__ G,
                                                  const int* __restrict__ csr,
                                                  const int* __restrict__ offs,
                                                  const float* __restrict__ dinv,
                                                  const float* __restrict__ bias,
                                                  __hip_bfloat16* __restrict__ A, int nodes) {
    const int p = blockIdx.y;                 // channel chunk 0..3
    const int lane = threadIdx.x & 63;
    const int wv = threadIdx.x >> 6;
    const int g = lane >> 4;                  // node group within wave
    const int t = lane & 15;                  // lane within group
    const int node = blockIdx.x * 16 + wv * 4 + g;
    if (node >= nodes) return;
    const int c0 = p * 32 + t * 2;
    const int beg = offs[node], end = offs[node + 1];
    const int gbase = g * 16;
    float ax = 0.f, ay = 0.f;
    for (int base = beg; base < end; base += 16) {
        const int cnt = min(16, end - base);
        int myidx = (t < cnt) ? csr[base + t] : 0;
        int j = 0;
        for (; j + 8 <= cnt; j += 8) {
#pragma unroll
            for (int u = 0; u < 8; ++u) {
                int idx = __shfl(myidx, gbase + j + u);
                __hip_bfloat162 hv = *(const __hip_bfloat162*)(G + (size_t)idx * C + c0);
                float2 f = __bfloat1622float2(hv);
                ax += f.x;
                ay += f.y;
            }
        }
        for (; j < cnt; ++j) {
            int idx = __shfl(myidx, gbase + j);
            __hip_bfloat162 hv = *(const __hip_bfloat162*)(G + (size_t)idx * C + c0);
            float2 f = __bfloat1622float2(hv);
            ax += f.x;
            ay += f.y;
        }
    }
    float d = dinv[node];
    float ox = fmaxf(ax * d + bias[c0], 0.f);
    float oy = fmaxf(ay * d + bias[c0 + 1], 0.f);
    __hip_bfloat162 o = __float22bfloat162_rn(make_float2(ox, oy));
    *(__hip_bfloat162*)(A + (size_t)node * C + c0) = o;
}

// ---------------- fused masked pool: pooled[b,c] = sum_n mask*(A1+A2+A3) ----------------
__global__ __launch_bounds__(64) void pool3_kernel(const __hip_bfloat16* __restrict__ S1,
                                                   const __hip_bfloat16* __restrict__ S2,
                                                   const __hip_bfloat16* __restrict__ S3,
                                                   const int* __restrict__ mask,
                                                   float* __restrict__ pooled, int N) {
    const int b = blockIdx.y;
    const int n0 = blockIdx.x * 128;
    const int c0 = threadIdx.x * 2;
    const int lim = min(n0 + 128, N);
    float ax = 0.f, ay = 0.f;
    for (int n = n0; n < lim; ++n) {
        if (mask[b * N + n]) {
            size_t o = ((size_t)b * N + n) * C + c0;
            float2 f1 = __bfloat1622float2(*(const __hip_bfloat162*)(S1 + o));
            float2 f2 = __bfloat1622float2(*(const __hip_bfloat162*)(S2 + o));
            float2 f3 = __bfloat1622float2(*(const __hip_bfloat162*)(S3 + o));
            ax += f1.x + f2.x + f3.x;
            ay += f1.y + f2.y + f3.y;
        }
    }
    atomicAdd(&pooled[b * C + c0], ax);
    atomicAdd(&pooled[b * C + c0 + 1], ay);
}

// ---------------- MLP head: [4,128]->256->64->16->1 ----------------
__global__ __launch_bounds__(256) void mlp_kernel(const float* __restrict__ pooled,
        const float* __restrict__ lw1, const float* __restrict__ lb1,
        const float* __restrict__ lw2, const float* __restrict__ lb2,
        const float* __restrict__ lw3, const float* __restrict__ lb3,
        const float* __restrict__ lw4, const float* __restrict__ lb4,
        float* __restrict__ out) {
    __shared__ float p[4 * 128];
    __shared__ float z1[4 * 256];
    __shared__ float z2[4 * 64];
    __shared__ float z3[4 * 16];
    const int tid = threadIdx.x;
    for (int i = tid; i < 4 * 128; i += 256) p[i] = pooled[i];
    __syncthreads();
    for (int o = tid; o < 4 * 256; o += 256) {
        int b = o >> 8, j = o & 255;
        float s = lb1[j];
        for (int k = 0; k < 128; ++k) s += p[b * 128 + k] * lw1[k * 256 + j];
        z1[o] = fmaxf(s, 0.f);
    }
    __syncthreads();
    for (int o = tid; o < 4 * 64; o += 256) {
        int b = o >> 6, j = o & 63;
        float s = lb2[j];
        for (int k = 0; k < 256; ++k) s += z1[b * 256 + k] * lw2[k * 64 + j];
        z2[o] = fmaxf(s, 0.f);
    }
    __syncthreads();
    if (tid < 64) {
        int b = tid >> 4, j = tid & 15;
        float s = lb3[j];
        for (int k = 0; k < 64; ++k) s += z2[b * 64 + k] * lw3[k * 16 + j];
        z3[tid] = fmaxf(s, 0.f);
    }
    __syncthreads();
    if (tid < 4) {
        float s = lb4[0];
        for (int k = 0; k < 16; ++k) s += z3[tid * 16 + k] * lw4[k];
        out[tid] = s;
    }
}

// ---------------- launcher ----------------

extern "C" void kernel_launch(void* const* d_in, const int* in_sizes, int n_in,
                              void* d_out, int out_size, void* d_ws, size_t ws_size,
                              hipStream_t stream) {
    const float* x    = (const float*)d_in[0];
    const int*   ei   = (const int*)d_in[1];
    const int*   pmask = (const int*)d_in[2];
    const float* W1 = (const float*)d_in[3];  const float* b1 = (const float*)d_in[4];
    const float* W2 = (const float*)d_in[5];  const float* b2 = (const float*)d_in[6];
    const float* W3 = (const float*)d_in[7];  const float* b3 = (const float*)d_in[8];
    const float* lw1 = (const float*)d_in[9];  const float* lb1 = (const float*)d_in[10];
    const float* lw2 = (const float*)d_in[11]; const float* lb2 = (const float*)d_in[12];
    const float* lw3 = (const float*)d_in[13]; const float* lb3 = (const float*)d_in[14];
    const float* lw4 = (const float*)d_in[15]; const float* lb4 = (const float*)d_in[16];
    float* out = (float*)d_out;

    const int E = in_sizes[1] / 2;
    const int NODES = in_sizes[0] / F_IN;
    const int NB = 4;
    const int NPER = NODES / NB;   // 17000
    const int NBUK = (NODES + 255) >> 8;
    const int NBLK = (E + CHUNK - 1) / CHUNK;
    const int* esrc = ei;
    const int* edst = ei + E;

    char* w = (char*)d_ws;
    size_t off = 0;
    auto alloc = [&](size_t bytes) -> void* {
        void* p = w + off;
        off = align256(off + bytes);
        return p;
    };
    float* dinv = (float*)alloc((size_t)NODES * 4);
    int*   offs = (int*)  alloc((size_t)(NODES + 1) * 4);
    int*   ebase = (int*) alloc((size_t)(NBUK + 1) * 4);
    int*   gcur = (int*)  alloc((size_t)NBUK * 4);
    int*   btot = (int*)  alloc((size_t)NBUK * 4);
    int2*  ebuf = (int2*) alloc((size_t)E * 8);
    int*   csr  = (int*)  alloc((size_t)(E + NODES) * 4);
    __hip_bfloat16* G   = (__hip_bfloat16*)alloc((size_t)NODES * C * 2);
    __hip_bfloat16* A1  = (__hip_bfloat16*)alloc((size_t)NODES * C * 2);
    __hip_bfloat16* A2  = (__hip_bfloat16*)alloc((size_t)NODES * C * 2);
    __hip_bfloat16* A3  = (__hip_bfloat16*)alloc((size_t)NODES * C * 2);
    __hip_bfloat16* Wsw1 = (__hip_bfloat16*)alloc((size_t)F_IN * C * 2);
    __hip_bfloat16* Wsw2 = (__hip_bfloat16*)alloc((size_t)C * C * 2);
    __hip_bfloat16* Wsw3 = (__hip_bfloat16*)alloc((size_t)C * C * 2);
    float* pooled = (float*)alloc((size_t)4 * C * 4);
    (void)ws_size; (void)n_in; (void)out_size;

    hipMemsetAsync(pooled, 0, (size_t)4 * C * 4, stream);
    hipMemsetAsync(btot,   0, (size_t)NBUK * 4, stream);

    // weight swizzles upfront (off the inter-layer critical path)
    wswz_kernel<<<(F_IN / 32 * 512 + 255) / 256, 256, 0, stream>>>(W1, Wsw1, F_IN);
    wswz_kernel<<<(C / 32 * 512 + 255) / 256, 256, 0, stream>>>(W2, Wsw2, C);
    wswz_kernel<<<(C / 32 * 512 + 255) / 256, 256, 0, stream>>>(W3, Wsw3, C);

    histA_kernel<<<NBLK, 256, 0, stream>>>(edst, btot, E, NBUK);
    bscan_kernel<<<1, 256, 0, stream>>>(btot, NBUK, ebase, gcur);
    partition_kernel<<<NBLK, 256, 0, stream>>>(esrc, edst, gcur, ebuf, E);
    csr_build_kernel<<<NBUK, 256, 0, stream>>>(ebuf, ebase, offs, dinv, csr, NODES);

    const int gblocks128 = (NODES + 127) / 128;
    dim3 agrid((NODES + 15) / 16, 4);   // x: node groups of 16, y: channel chunk

    // layer 1 (K = 256, fp32 input fused-converted)
    mfma_gemm_kernel<true><<<gblocks128, 256, F_IN * 256, stream>>>(x, Wsw1, dinv, G, NODES, F_IN);
    agg_kernel<<<agrid, 256, 0, stream>>>(G, csr, offs, dinv, b1, A1, NODES);
    // layer 2 (K = 128)
    mfma_gemm_kernel<false><<<gblocks128, 256, C * 256, stream>>>(A1, Wsw2, dinv, G, NODES, C);
    agg_kernel<<<agrid, 256, 0, stream>>>(G, csr, offs, dinv, b2, A2, NODES);
    // layer 3 (K = 128)
    mfma_gemm_kernel<false><<<gblocks128, 256, C * 256, stream>>>(A2, Wsw3, dinv, G, NODES, C);
    agg_kernel<<<agrid, 256, 0, stream>>>(G, csr, offs, dinv, b3, A3, NODES);

    // fused residual pool + MLP head
    dim3 pgrid((NPER + 127) / 128, NB);
    pool3_kernel<<<pgrid, 64, 0, stream>>>(A1, A2, A3, pmask, pooled, NPER);
    mlp_kernel<<<1, 256, 0, stream>>>(pooled, lw1, lb1, lw2, lb2, lw3, lb3, lw4, lb4, out);
}

// Round 12
// 496.782 us; speedup vs baseline: 1.3053x; 1.3053x over previous
//
#include <hip/hip_runtime.h>
#include <hip/hip_bf16.h>
#include <cstdint>

#define F_IN 256
#define C 128
#define NBUK_MAX 320     // supports NODES <= 81920 (bucket = dst >> 8)
#define CHUNK 4096       // edges per partition block
#define CAP 12288        // per-bucket slab capacity (mean ~8180, max ~8500)

typedef short bf8_t __attribute__((ext_vector_type(8)));   // 8 bf16 bit-patterns (4 VGPRs)
typedef float f4_t  __attribute__((ext_vector_type(4)));

static inline size_t align256(size_t x) { return (x + 255) & ~(size_t)255; }

// ---------------- graph preprocessing ----------------

// Partition edges by bucket (dst>>8) straight into per-bucket slabs ebuf[b*CAP ...].
// Per-block LDS staging -> grouped writes; slab space reserved via atomicAdd(cnt[b]).
__global__ __launch_bounds__(256) void partition_kernel(const int* __restrict__ src,
                                                        const int* __restrict__ dst,
                                                        int* __restrict__ cntb,
                                                        int2* __restrict__ ebuf, int E) {
    __shared__ int hist[NBUK_MAX];
    __shared__ int base[NBUK_MAX];
    __shared__ int gbase[NBUK_MAX];
    __shared__ int2 stage[CHUNK];
    const int tid = threadIdx.x;
    const int e0 = blockIdx.x * CHUNK;
    const int cnt = min(CHUNK, E - e0);

    for (int i = tid; i < NBUK_MAX; i += 256) hist[i] = 0;
    __syncthreads();

    int2 ev[CHUNK / 256];
    int mo[CHUNK / 256];
#pragma unroll
    for (int k = 0; k < CHUNK / 256; ++k) {
        int e = e0 + k * 256 + tid;
        if (e < E) {
            int2 v;
            v.x = src[e];
            v.y = dst[e];
            ev[k] = v;
            mo[k] = atomicAdd(&hist[v.y >> 8], 1);
        }
    }
    __syncthreads();
    // exclusive scan of hist (320 entries) by wave 0: 5 buckets/lane + shuffle scan
    if (tid < 64) {
        int acc[5];
        int s = 0;
#pragma unroll
        for (int j = 0; j < 5; ++j) {
            int idx = tid * 5 + j;
            acc[j] = s;
            s += hist[idx];
        }
        int tot = s;
#pragma unroll
        for (int d = 1; d < 64; d <<= 1) {
            int o = __shfl_up(tot, d);
            if (tid >= d) tot += o;
        }
        int excl = tot - s;
#pragma unroll
        for (int j = 0; j < 5; ++j) base[tid * 5 + j] = excl + acc[j];
    }
    __syncthreads();
    // reserve slab ranges (one atomic per nonempty bucket)
    for (int i = tid; i < NBUK_MAX; i += 256) {
        int h = hist[i];
        gbase[i] = h ? atomicAdd(&cntb[i], h) : 0;
    }
    __syncthreads();
    // scatter into LDS staging grouped by bucket
#pragma unroll
    for (int k = 0; k < CHUNK / 256; ++k) {
        int e = e0 + k * 256 + tid;
        if (e < E) stage[base[ev[k].y >> 8] + mo[k]] = ev[k];
    }
    __syncthreads();
    // grouped write-out: consecutive staged entries -> consecutive slab slots
    for (int i = tid; i < cnt; i += 256) {
        int2 e = stage[i];
        int b = e.y >> 8;
        ebuf[(size_t)b * CAP + gbase[b] + (i - base[b])] = e;
    }
}

// Single block: exclusive-scan 266 bucket counts (wave-0 shuffle scan) -> ebase.
__global__ __launch_bounds__(256) void bscan_kernel(const int* __restrict__ cntb,
                                                    int nbuk,
                                                    int* __restrict__ ebase) {
    __shared__ int sums[NBUK_MAX];
    __shared__ int base[NBUK_MAX + 1];
    const int tid = threadIdx.x;
    for (int bk = tid; bk < NBUK_MAX; bk += 256)
        sums[bk] = (bk < nbuk) ? cntb[bk] : 0;
    __syncthreads();
    if (tid < 64) {
        int acc[5];
        int s = 0;
#pragma unroll
        for (int j = 0; j < 5; ++j) {
            acc[j] = s;
            s += sums[tid * 5 + j];
        }
        int tot = s;
#pragma unroll
        for (int d = 1; d < 64; d <<= 1) {
            int o = __shfl_up(tot, d);
            if (tid >= d) tot += o;
        }
        int excl = tot - s;
#pragma unroll
        for (int j = 0; j < 5; ++j) base[tid * 5 + j] = excl + acc[j];
        if (tid == 63) base[320] = tot;
    }
    __syncthreads();
    for (int bk = tid; bk <= nbuk; bk += 256)
        ebase[bk] = base[bk];
}

// Per-bucket CSR build from the bucket slab. Degree count in LDS, local scan -> offs,
// dinv, CSR fill with self-loop head. All node-level work confined to the bucket.
__global__ __launch_bounds__(256) void csr_build_kernel(const int2* __restrict__ ebuf,
                                                        const int* __restrict__ ebase,
                                                        int* __restrict__ offs,
                                                        float* __restrict__ dinv,
                                                        int* __restrict__ csr, int nodes) {
    __shared__ int deg[256];
    __shared__ int p[256];
    __shared__ int pre[257];   // exclusive prefix of deg
    __shared__ int cur[256];
    const int b = blockIdx.x;
    const int n0 = b << 8;
    const int ncnt = min(256, nodes - n0);
    const int tid = threadIdx.x;
    const int eb = ebase[b];
    const int cntE = ebase[b + 1] - eb;
    const int2* slab = ebuf + (size_t)b * CAP;

    deg[tid] = 0;
    __syncthreads();
    for (int k = tid; k < cntE; k += 256)
        atomicAdd(&deg[slab[k].y & 255], 1);
    __syncthreads();
    p[tid] = deg[tid];
    __syncthreads();
    for (int d = 1; d < 256; d <<= 1) {
        int v = (tid >= d) ? p[tid - d] : 0;
        __syncthreads();
        p[tid] += v;
        __syncthreads();
    }
    pre[tid + 1] = p[tid];
    if (tid == 0) pre[0] = 0;
    __syncthreads();

    // offs[n0+i] = eb + pre[i] + n0 + i  (each preceding node adds 1 self-loop)
    for (int i = tid; i <= ncnt; i += 256)
        offs[n0 + i] = eb + pre[i] + n0 + i;
    if (tid < ncnt) {
        dinv[n0 + tid] = rsqrtf((float)(deg[tid] + 1));
        csr[eb + pre[tid] + n0 + tid] = n0 + tid;   // self-loop head
    }
    cur[tid] = 0;
    __syncthreads();
    for (int k = tid; k < cntE; k += 256) {
        int2 e = slab[k];
        int loc = e.y & 255;
        int q = atomicAdd(&cur[loc], 1);
        csr[eb + pre[loc] + n0 + loc + 1 + q] = e.x;
    }
}

// ---------------- W swizzle: fp32 [K,128] -> bf16 MFMA B-frag order ----------------
// entry id i = (t*8 + u)*64 + l  ->  8 bf16: W[t*32 + (l>>4)*8 + j][u*16 + (l&15)]
static __device__ inline unsigned pack_bf16(float a, float b) {
    __hip_bfloat162 h = __float22bfloat162_rn(make_float2(a, b));
    return *(unsigned*)&h;
}

static __device__ inline void swz_one(const float* __restrict__ W,
                                      __hip_bfloat16* __restrict__ Wsw, int i) {
    int l = i & 63;
    int u = (i >> 6) & 7;
    int t = i >> 9;
    int krow = t * 32 + (l >> 4) * 8;
    int col = u * 16 + (l & 15);
    unsigned packed[4];
#pragma unroll
    for (int j = 0; j < 4; ++j) {
        float a = W[(size_t)(krow + 2 * j) * C + col];
        float b = W[(size_t)(krow + 2 * j + 1) * C + col];
        packed[j] = pack_bf16(a, b);
    }
    uint4 o = make_uint4(packed[0], packed[1], packed[2], packed[3]);
    *(uint4*)(Wsw + (size_t)i * 8) = o;
}

// all three weights in one launch: entries [0,4096) = W1(K=256), then 2048 each for W2, W3
__global__ __launch_bounds__(256) void wswz_all_kernel(const float* __restrict__ W1,
                                                       const float* __restrict__ W2,
                                                       const float* __restrict__ W3,
                                                       __hip_bfloat16* __restrict__ Wsw1,
                                                       __hip_bfloat16* __restrict__ Wsw2,
                                                       __hip_bfloat16* __restrict__ Wsw3) {
    int i = blockIdx.x * blockDim.x + threadIdx.x;
    if (i < 4096)      swz_one(W1, Wsw1, i);
    else if (i < 6144) swz_one(W2, Wsw2, i - 4096);
    else if (i < 8192) swz_one(W3, Wsw3, i - 6144);
}

// ---------------- MFMA GEMM: G[M,128] = bf16( dinv[row] * (X[M,K] @ W) ) ----------------
// block: 256 threads = 4 waves, 128 rows (2 m-tiles/wave); W staged in 32KB LDS chunks
// (4 k-tiles at a time) so occupancy is 4 blocks/CU even at K=256; A prefetch 1 K-step.

static __device__ inline bf8_t pack8(float4 u0, float4 u1) {
    union { unsigned u[4]; bf8_t v; } r;
    r.u[0] = pack_bf16(u0.x, u0.y);
    r.u[1] = pack_bf16(u0.z, u0.w);
    r.u[2] = pack_bf16(u1.x, u1.y);
    r.u[3] = pack_bf16(u1.z, u1.w);
    return r.v;
}

template <bool F32IN>
__global__ __launch_bounds__(256) void mfma_gemm_kernel(const void* __restrict__ Xv,
                                                        const __hip_bfloat16* __restrict__ Wsw,
                                                        const float* __restrict__ dinv,
                                                        __hip_bfloat16* __restrict__ G,
                                                        int M, int K) {
    __shared__ char lds[32768];   // 4 k-tiles x 8KB
    const int tid = threadIdx.x;
    const int l = tid & 63;
    const int w = tid >> 6;
    const int lm = l & 15;
    const int lk = (l >> 4) * 8;
    const int row0 = blockIdx.x * 128 + w * 32;

    f4_t acc[2][8] = {};
    const int steps = K >> 5;

    const float* xf[2];
    const __hip_bfloat16* xb[2];
#pragma unroll
    for (int mt = 0; mt < 2; ++mt) {
        int r = min(row0 + mt * 16 + lm, M - 1);
        xf[mt] = (const float*)Xv + (size_t)r * K + lk;
        xb[mt] = (const __hip_bfloat16*)Xv + (size_t)r * K + lk;
    }

    float4 cf[2][2];
    bf8_t cb[2];
#pragma unroll
    for (int mt = 0; mt < 2; ++mt) {
        if (F32IN) {
            cf[mt][0] = *(const float4*)(xf[mt]);
            cf[mt][1] = *(const float4*)(xf[mt] + 4);
        } else {
            cb[mt] = *(const bf8_t*)(xb[mt]);
        }
    }

    for (int s = 0; s < steps; ++s) {
        if ((s & 3) == 0) {               // stage next 4 k-tiles (32 KB) of W
            if (s) __syncthreads();
            const char* wsrc = (const char*)Wsw + (size_t)s * 8192;
            for (int o = tid * 16; o < 32768; o += 256 * 16)
                *(uint4*)(lds + o) = *(const uint4*)(wsrc + o);
            __syncthreads();
        }
        float4 nf[2][2];
        bf8_t nb[2];
        if (s + 1 < steps) {
#pragma unroll
            for (int mt = 0; mt < 2; ++mt) {
                if (F32IN) {
                    nf[mt][0] = *(const float4*)(xf[mt] + (s + 1) * 32);
                    nf[mt][1] = *(const float4*)(xf[mt] + (s + 1) * 32 + 4);
                } else {
                    nb[mt] = *(const bf8_t*)(xb[mt] + (s + 1) * 32);
                }
            }
        }
        bf8_t a[2];
#pragma unroll
        for (int mt = 0; mt < 2; ++mt)
            a[mt] = F32IN ? pack8(cf[mt][0], cf[mt][1]) : cb[mt];

        const char* bbase = lds + ((size_t)((s & 3) * 8) * 64 + l) * 16;
#pragma unroll
        for (int u = 0; u < 8; ++u) {
            bf8_t b = *(const bf8_t*)(bbase + (size_t)u * 64 * 16);
#pragma unroll
            for (int mt = 0; mt < 2; ++mt)
                acc[mt][u] = __builtin_amdgcn_mfma_f32_16x16x32_bf16(a[mt], b, acc[mt][u], 0, 0, 0);
        }
#pragma unroll
        for (int mt = 0; mt < 2; ++mt) {
            if (F32IN) {
                cf[mt][0] = nf[mt][0];
                cf[mt][1] = nf[mt][1];
            } else {
                cb[mt] = nb[mt];
            }
        }
    }

    // epilogue: C/D map col=lane&15, row=(lane>>4)*4+reg; scale by dinv[row]
#pragma unroll
    for (int mt = 0; mt < 2; ++mt) {
        int rbase = row0 + mt * 16 + (l >> 4) * 4;
#pragma unroll
        for (int r = 0; r < 4; ++r) {
            int row = rbase + r;
            if (row < M) {
                float dv = dinv[row];
#pragma unroll
                for (int u = 0; u < 8; ++u) {
                    float v = acc[mt][u][r] * dv;
                    G[(size_t)row * C + u * 16 + lm] = __float2bfloat16(v);
                }
            }
        }
    }
}

// ---------------- aggregation: A[i] = relu(dinv[i]*sum_{j in csr[i]} G[j] + bias) ----------------
// 4 nodes per 256-thread block (1 wave/node): full occupancy, few dispatches. (R10 winner.)
__global__ __launch_bounds__(256) void agg_kernel(const __hip_bfloat16* __restrict__ G,
                                                  const int* __restrict__ csr,
                                                  const int* __restrict__ offs,
                                                  const float* __restrict__ dinv,
                                                  const float* __restrict__ bias,
                                                  __hip_bfloat16* __restrict__ A, int nodes) {
    const int node = blockIdx.x * 4 + (threadIdx.x >> 6);
    if (node >= nodes) return;
    const int tid = threadIdx.x & 63;
    const int c0 = tid * 2;
    const int beg = offs[node], end = offs[node + 1];
    float ax = 0.f, ay = 0.f;
    for (int base = beg; base < end; base += 64) {
        const int cnt = min(64, end - base);
        int myidx = (tid < cnt) ? csr[base + tid] : 0;
        int j = 0;
        for (; j + 8 <= cnt; j += 8) {
#pragma unroll
            for (int u = 0; u < 8; ++u) {
                int idx = __shfl(myidx, j + u);
                __hip_bfloat162 hv = *(const __hip_bfloat162*)(G + (size_t)idx * C + c0);
                float2 f = __bfloat1622float2(hv);
                ax += f.x;
                ay += f.y;
            }
        }
        for (; j < cnt; ++j) {
            int idx = __shfl(myidx, j);
            __hip_bfloat162 hv = *(const __hip_bfloat162*)(G + (size_t)idx * C + c0);
            float2 f = __bfloat1622float2(hv);
            ax += f.x;
            ay += f.y;
        }
    }
    float d = dinv[node];
    float ox = fmaxf(ax * d + bias[c0], 0.f);
    float oy = fmaxf(ay * d + bias[c0 + 1], 0.f);
    __hip_bfloat162 o = __float22bfloat162_rn(make_float2(ox, oy));
    *(__hip_bfloat162*)(A + (size_t)node * C + c0) = o;
}

// ---------------- fused masked pool: pooled[b,c] = sum_n mask*(A1+A2+A3) ----------------
__global__ __launch_bounds__(64) void pool3_kernel(const __hip_bfloat16* __restrict__ S1,
                                                   const __hip_bfloat16* __restrict__ S2,
                                                   const __hip_bfloat16* __restrict__ S3,
                                                   const int* __restrict__ mask,
                                                   float* __restrict__ pooled, int N) {
    const int b = blockIdx.y;
    const int n0 = blockIdx.x * 128;
    const int c0 = threadIdx.x * 2;
    const int lim = min(n0 + 128, N);
    float ax = 0.f, ay = 0.f;
    for (int n = n0; n < lim; ++n) {
        if (mask[b * N + n]) {
            size_t o = ((size_t)b * N + n) * C + c0;
            float2 f1 = __bfloat1622float2(*(const __hip_bfloat162*)(S1 + o));
            float2 f2 = __bfloat1622float2(*(const __hip_bfloat162*)(S2 + o));
            float2 f3 = __bfloat1622float2(*(const __hip_bfloat162*)(S3 + o));
            ax += f1.x + f2.x + f3.x;
            ay += f1.y + f2.y + f3.y;
        }
    }
    atomicAdd(&pooled[b * C + c0], ax);
    atomicAdd(&pooled[b * C + c0 + 1], ay);
}

// ---------------- MLP head: [4,128]->256->64->16->1 ----------------
__global__ __launch_bounds__(256) void mlp_kernel(const float* __restrict__ pooled,
        const float* __restrict__ lw1, const float* __restrict__ lb1,
        const float* __restrict__ lw2, const float* __restrict__ lb2,
        const float* __restrict__ lw3, const float* __restrict__ lb3,
        const float* __restrict__ lw4, const float* __restrict__ lb4,
        float* __restrict__ out) {
    __shared__ float p[4 * 128];
    __shared__ float z1[4 * 256];
    __shared__ float z2[4 * 64];
    __shared__ float z3[4 * 16];
    const int tid = threadIdx.x;
    for (int i = tid; i < 4 * 128; i += 256) p[i] = pooled[i];
    __syncthreads();
    for (int o = tid; o < 4 * 256; o += 256) {
        int b = o >> 8, j = o & 255;
        float s = lb1[j];
        for (int k = 0; k < 128; ++k) s += p[b * 128 + k] * lw1[k * 256 + j];
        z1[o] = fmaxf(s, 0.f);
    }
    __syncthreads();
    for (int o = tid; o < 4 * 64; o += 256) {
        int b = o >> 6, j = o & 63;
        float s = lb2[j];
        for (int k = 0; k < 256; ++k) s += z1[b * 256 + k] * lw2[k * 64 + j];
        z2[o] = fmaxf(s, 0.f);
    }
    __syncthreads();
    if (tid < 64) {
        int b = tid >> 4, j = tid & 15;
        float s = lb3[j];
        for (int k = 0; k < 64; ++k) s += z2[b * 64 + k] * lw3[k * 16 + j];
        z3[tid] = fmaxf(s, 0.f);
    }
    __syncthreads();
    if (tid < 4) {
        float s = lb4[0];
        for (int k = 0; k < 16; ++k) s += z3[tid * 16 + k] * lw4[k];
        out[tid] = s;
    }
}

// ---------------- launcher ----------------

extern "C" void kernel_launch(void* const* d_in, const int* in_sizes, int n_in,
                              void* d_out, int out_size, void* d_ws, size_t ws_size,
                              hipStream_t stream) {
    const float* x    = (const float*)d_in[0];
    const int*   ei   = (const int*)d_in[1];
    const int*   pmask = (const int*)d_in[2];
    const float* W1 = (const float*)d_in[3];  const float* b1 = (const float*)d_in[4];
    const float* W2 = (const float*)d_in[5];  const float* b2 = (const float*)d_in[6];
    const float* W3 = (const float*)d_in[7];  const float* b3 = (const float*)d_in[8];
    const float* lw1 = (const float*)d_in[9];  const float* lb1 = (const float*)d_in[10];
    const float* lw2 = (const float*)d_in[11]; const float* lb2 = (const float*)d_in[12];
    const float* lw3 = (const float*)d_in[13]; const float* lb3 = (const float*)d_in[14];
    const float* lw4 = (const float*)d_in[15]; const float* lb4 = (const float*)d_in[16];
    float* out = (float*)d_out;

    const int E = in_sizes[1] / 2;
    const int NODES = in_sizes[0] / F_IN;
    const int NB = 4;
    const int NPER = NODES / NB;   // 17000
    const int NBUK = (NODES + 255) >> 8;
    const int NBLK = (E + CHUNK - 1) / CHUNK;
    const int* esrc = ei;
    const int* edst = ei + E;

    char* w = (char*)d_ws;
    size_t off = 0;
    auto alloc = [&](size_t bytes) -> void* {
        void* p = w + off;
        off = align256(off + bytes);
        return p;
    };
    float* dinv = (float*)alloc((size_t)NODES * 4);
    int*   offs = (int*)  alloc((size_t)(NODES + 1) * 4);
    int*   ebase = (int*) alloc((size_t)(NBUK + 1) * 4);
    int*   cntb = (int*)  alloc((size_t)NBUK * 4);
    int2*  ebuf = (int2*) alloc((size_t)NBUK * CAP * 8);
    int*   csr  = (int*)  alloc((size_t)(E + NODES) * 4);
    __hip_bfloat16* G   = (__hip_bfloat16*)alloc((size_t)NODES * C * 2);
    __hip_bfloat16* A1  = (__hip_bfloat16*)alloc((size_t)NODES * C * 2);
    __hip_bfloat16* A2  = (__hip_bfloat16*)alloc((size_t)NODES * C * 2);
    __hip_bfloat16* A3  = (__hip_bfloat16*)alloc((size_t)NODES * C * 2);
    __hip_bfloat16* Wsw1 = (__hip_bfloat16*)alloc((size_t)F_IN * C * 2);
    __hip_bfloat16* Wsw2 = (__hip_bfloat16*)alloc((size_t)C * C * 2);
    __hip_bfloat16* Wsw3 = (__hip_bfloat16*)alloc((size_t)C * C * 2);
    float* pooled = (float*)alloc((size_t)4 * C * 4);
    (void)ws_size; (void)n_in; (void)out_size;

    hipMemsetAsync(cntb,   0, (size_t)NBUK * 4, stream);
    hipMemsetAsync(pooled, 0, (size_t)4 * C * 4, stream);

    // all weight swizzles in one launch (off the inter-layer critical path)
    wswz_all_kernel<<<32, 256, 0, stream>>>(W1, W2, W3, Wsw1, Wsw2, Wsw3);

    partition_kernel<<<NBLK, 256, 0, stream>>>(esrc, edst, cntb, ebuf, E);
    bscan_kernel<<<1, 256, 0, stream>>>(cntb, NBUK, ebase);
    csr_build_kernel<<<NBUK, 256, 0, stream>>>(ebuf, ebase, offs, dinv, csr, NODES);

    const int gblocks128 = (NODES + 127) / 128;
    const int ablocks = (NODES + 3) / 4;

    // layer 1 (K = 256, fp32 input fused-converted)
    mfma_gemm_kernel<true><<<gblocks128, 256, 0, stream>>>(x, Wsw1, dinv, G, NODES, F_IN);
    agg_kernel<<<ablocks, 256, 0, stream>>>(G, csr, offs, dinv, b1, A1, NODES);
    // layer 2 (K = 128)
    mfma_gemm_kernel<false><<<gblocks128, 256, 0, stream>>>(A1, Wsw2, dinv, G, NODES, C);
    agg_kernel<<<ablocks, 256, 0, stream>>>(G, csr, offs, dinv, b2, A2, NODES);
    // layer 3 (K = 128)
    mfma_gemm_kernel<false><<<gblocks128, 256, 0, stream>>>(A2, Wsw3, dinv, G, NODES, C);
    agg_kernel<<<ablocks, 256, 0, stream>>>(G, csr, offs, dinv, b3, A3, NODES);

    // fused residual pool + MLP head
    dim3 pgrid((NPER + 127) / 128, NB);
    pool3_kernel<<<pgrid, 64, 0, stream>>>(A1, A2, A3, pmask, pooled, NPER);
    mlp_kernel<<<1, 256, 0, stream>>>(pooled, lw1, lb1, lw2, lb2, lw3, lb3, lw4, lb4, out);
}